// Round 2
// baseline (974.519 us; speedup 1.0000x reference)
//
#include <hip/hip_runtime.h>

#define B_SZ  4096
#define T_LEN 1024
#define VOCAB 32000
#define HID   16
#define CHB   8                  // chains (batches) per block
#define NBLK  (B_SZ / CHB)       // 512 blocks

#define S2LE 2.8853900817779268f // 2*log2(e): e^{2x} = 2^{S2LE*x}

template<int CTRL>
__device__ __forceinline__ float dpp_f(float x) {
  int r = __builtin_amdgcn_update_dpp(0, __float_as_int(x), CTRL, 0xF, 0xF, false);
  return __int_as_float(r);
}

// DPP ctrl encodings (gfx9/CDNA):
//   quad_perm bcast k: k*0x55  (0x00, 0x55, 0xAA, 0xFF)
//   row_ror:8       = 0x128    (quad q -> q^2 within row of 16)
//   row_mirror      = 0x140    (quad q -> q^3, lane reversed in quad)
//   row_half_mirror = 0x141    (quad q -> q^1, lane reversed in quad)

// E2[v][i] = S2LE * (sum_j Wx_w[i][j] * embed[v][j] + Wx_b[i])
// Pre-scaled by 2*log2(e) so the recurrent chain feeds v_exp_f32 directly.
__global__ __launch_bounds__(256) void e2_kernel(
    const float* __restrict__ embed, const float* __restrict__ Wxw,
    const float* __restrict__ Wxb, float* __restrict__ E2) {
  int tid = blockIdx.x * 256 + threadIdx.x;   // 512000 threads
  int v = tid >> 4, i = tid & 15;
  const float4* er = (const float4*)(embed + (size_t)v * HID);
  const float4* wr = (const float4*)(Wxw + (size_t)i * HID);
  float acc = Wxb[i];
#pragma unroll
  for (int q = 0; q < 4; ++q) {
    float4 e4 = er[q], w4 = wr[q];
    acc = fmaf(w4.x, e4.x, acc);
    acc = fmaf(w4.y, e4.y, acc);
    acc = fmaf(w4.z, e4.z, acc);
    acc = fmaf(w4.w, e4.w, acc);
  }
  E2[tid] = acc * S2LE;
}

// Fused RNN + output projection. One block = 8 batches.
// Phase A (threads 0..127): 8 recurrent chains, one per 16 lanes, h all-gather
//   via pure-VALU DPP. Wh rows pre-scaled by S2LE so tanh needs no mul:
//   h = 1 - 2*rcp(exp2(acc)+1).
// Phase B (all 256 threads): out[b][v] for the block's 8 batches; h handed
//   off through 512 B of LDS; outw weights held in regs, reused over 8 rows.
__global__ __launch_bounds__(256) void rnn_out(
    const int* __restrict__ seq, const float* __restrict__ E2,
    const float* __restrict__ Wh, const float* __restrict__ outw,
    const float* __restrict__ outb, float* __restrict__ out) {
  __shared__ float hsh[CHB][HID];

  if (threadIdx.x < CHB * HID) {
    int c = threadIdx.x >> 4, i = threadIdx.x & 15;
    int b = blockIdx.x * CHB + c;
    int q = (threadIdx.x >> 2) & 3;           // quad index within 16-lane row

    float4 wp[4];
    const float* whrow = Wh + (size_t)i * HID;
#pragma unroll
    for (int t = 0; t < 4; ++t) {
      float4 w4 = *(const float4*)(whrow + 4 * (q ^ t));
      wp[t].x = w4.x * S2LE; wp[t].y = w4.y * S2LE;
      wp[t].z = w4.z * S2LE; wp[t].w = w4.w * S2LE;
    }

    const int4*  seq4 = (const int4*)(seq + (size_t)b * T_LEN);
    const float* E2i  = E2 + i;

    float xpA[4];
    int4 idx1, idx2;
    {
      int4 i0 = seq4[0];
      idx1 = seq4[1];
      idx2 = seq4[2];
      xpA[0] = E2i[(size_t)i0.x * HID];
      xpA[1] = E2i[(size_t)i0.y * HID];
      xpA[2] = E2i[(size_t)i0.z * HID];
      xpA[3] = E2i[(size_t)i0.w * HID];
    }

    float hcur = 0.0f;

    for (int g = 0; g < T_LEN / 4; ++g) {
      int gn = (g + 3 < T_LEN / 4) ? (g + 3) : (T_LEN / 4 - 1);
      int4 idx3 = seq4[gn];
      float xpB[4];
      xpB[0] = E2i[(size_t)idx1.x * HID];
      xpB[1] = E2i[(size_t)idx1.y * HID];
      xpB[2] = E2i[(size_t)idx1.z * HID];
      xpB[3] = E2i[(size_t)idx1.w * HID];

#pragma unroll
      for (int s = 0; s < 4; ++s) {
        float b0 = dpp_f<0x00>(hcur);
        float b1 = dpp_f<0x55>(hcur);
        float b2 = dpp_f<0xAA>(hcur);
        float b3 = dpp_f<0xFF>(hcur);

        float c0 = dpp_f<0x141>(b0);          // q^1
        float c1 = dpp_f<0x141>(b1);
        float c2 = dpp_f<0x141>(b2);
        float c3 = dpp_f<0x141>(b3);

        float d0 = dpp_f<0x128>(b0);          // q^2
        float d1 = dpp_f<0x128>(b1);
        float d2 = dpp_f<0x128>(b2);
        float d3 = dpp_f<0x128>(b3);

        float e0 = dpp_f<0x140>(b0);          // q^3
        float e1 = dpp_f<0x140>(b1);
        float e2 = dpp_f<0x140>(b2);
        float e3 = dpp_f<0x140>(b3);

        float p0 = fmaf(wp[0].x, b0, xpA[s]);
        p0 = fmaf(wp[0].y, b1, p0);
        p0 = fmaf(wp[0].z, b2, p0);
        p0 = fmaf(wp[0].w, b3, p0);

        float p1 = wp[1].x * c0;
        p1 = fmaf(wp[1].y, c1, p1);
        p1 = fmaf(wp[1].z, c2, p1);
        p1 = fmaf(wp[1].w, c3, p1);

        float p2 = wp[2].x * d0;
        p2 = fmaf(wp[2].y, d1, p2);
        p2 = fmaf(wp[2].z, d2, p2);
        p2 = fmaf(wp[2].w, d3, p2);

        float p3 = wp[3].x * e0;
        p3 = fmaf(wp[3].y, e1, p3);
        p3 = fmaf(wp[3].z, e2, p3);
        p3 = fmaf(wp[3].w, e3, p3);

        float acc = (p0 + p1) + (p2 + p3);    // already scaled by 2*log2(e)
        float e  = __builtin_amdgcn_exp2f(acc);
        float r  = __builtin_amdgcn_rcpf(e + 1.0f);
        hcur = fmaf(-2.0f, r, 1.0f);          // tanh; tails: e->0 => -1, e->inf => 1
      }

#pragma unroll
      for (int s = 0; s < 4; ++s) xpA[s] = xpB[s];
      idx1 = idx2;
      idx2 = idx3;
    }

    hsh[c][i] = hcur;
  }

  __syncthreads();

  // Phase B: lane owns 4 consecutive v; wave covers 256 v; waves stripe the
  // 125 v-panels; weights reused across the block's 8 batch rows.
  int lane = threadIdx.x & 63;
  int wv   = threadIdx.x >> 6;
  int b0   = blockIdx.x * CHB;

  for (int vb = wv; vb < VOCAB / 256; vb += 4) {
    int v0 = vb * 256 + lane * 4;

    float w[4][16];
#pragma unroll
    for (int c = 0; c < 4; ++c) {
      const float4* wr = (const float4*)(outw + (size_t)(v0 + c) * HID);
#pragma unroll
      for (int qq = 0; qq < 4; ++qq) {
        float4 t = wr[qq];
        w[c][4*qq+0] = t.x; w[c][4*qq+1] = t.y;
        w[c][4*qq+2] = t.z; w[c][4*qq+3] = t.w;
      }
    }
    float4 ob = *(const float4*)(outb + v0);

#pragma unroll
    for (int r = 0; r < CHB; ++r) {
      const float4* hr = (const float4*)(&hsh[r][0]);
      float hv[16];
#pragma unroll
      for (int qq = 0; qq < 4; ++qq) {
        float4 t = hr[qq];                     // LDS broadcast read
        hv[4*qq+0] = t.x; hv[4*qq+1] = t.y;
        hv[4*qq+2] = t.z; hv[4*qq+3] = t.w;
      }
      float4 acc = ob;
#pragma unroll
      for (int k = 0; k < 16; ++k) {
        acc.x = fmaf(w[0][k], hv[k], acc.x);
        acc.y = fmaf(w[1][k], hv[k], acc.y);
        acc.z = fmaf(w[2][k], hv[k], acc.z);
        acc.w = fmaf(w[3][k], hv[k], acc.w);
      }
      *(float4*)(out + (size_t)(b0 + r) * VOCAB + v0) = acc;
    }
  }
}

extern "C" void kernel_launch(void* const* d_in, const int* in_sizes, int n_in,
                              void* d_out, int out_size, void* d_ws, size_t ws_size,
                              hipStream_t stream) {
  const int*   seq   = (const int*)  d_in[0];
  const float* embed = (const float*)d_in[1];
  const float* Wh    = (const float*)d_in[2];
  const float* Wxw   = (const float*)d_in[3];
  const float* Wxb   = (const float*)d_in[4];
  const float* outw  = (const float*)d_in[5];
  const float* outb  = (const float*)d_in[6];
  float* out  = (float*)d_out;

  float* E2 = (float*)d_ws;                   // 32000*16 fp32 = 2.048 MB

  e2_kernel<<<VOCAB * HID / 256, 256, 0, stream>>>(embed, Wxw, Wxb, E2);
  rnn_out<<<NBLK, 256, 0, stream>>>(seq, E2, Wh, outw, outb, out);
}